// Round 4
// baseline (598.240 us; speedup 1.0000x reference)
//
#include <hip/hip_runtime.h>
#include <hip/hip_bf16.h>

#define LNUM 6
#define BATCH 131072

typedef __bf16 bf16x8 __attribute__((ext_vector_type(8)));
typedef float f32x16 __attribute__((ext_vector_type(16)));
typedef float f32x4  __attribute__((ext_vector_type(4)));

// ---------------- ws layout ----------------
// 36 W blocks, each 256x256 bf16 = 131072 B:
// [nh(2)][kk(16)][nti(4)][lane(64)][16B]
//   n = (nh*4+nti)*32 + (l&31), k = kk*16 + (l>>5)*8 + jj
#define WFRAG_BYTES 131072ul
#define W1B1_OFF 4718592ul   // 12 x (256 f32 W1row || 256 f32 B1)
#define BIAS_OFF 4743168ul   // 36 x 256 f32 (B2/B3/B4)
#define W5_OFF   4780032ul   // 12 x 272 f32 (W5 column || B5 || pad)
#define WS_NEEDED 4793088ul

struct PtrPack { const float* p[21]; };

// -------- prep: pack W2/W3/W4 into MFMA fragment order (verified r4-r17) --------
__global__ void prep_w(PtrPack P, unsigned char* __restrict__ ws) {
    int t = blockIdx.x * 256 + threadIdx.x;
    int blk = t >> 13;
    int e8  = t & 8191;
    int nh  = e8 >> 12;
    int kk  = (e8 >> 8) & 15;
    int nti = (e8 >> 6) & 3;
    int l   = e8 & 63;
    int nt = nh * 4 + nti;
    int n  = nt * 32 + (l & 31);
    int k0 = kk * 16 + (l >> 5) * 8;
    int net = blk / 18, rem = blk % 18;
    int i = rem / 3, g = rem % 3;
    const float* src = P.p[3 + g * 2 + net * 10] + i * 65536;
    bf16x8 v;
#pragma unroll
    for (int jj = 0; jj < 8; ++jj) v[jj] = (__bf16)src[(k0 + jj) * 256 + n];
    *(bf16x8*)(ws + (unsigned long)blk * WFRAG_BYTES + (unsigned)e8 * 16) = v;
}

// -------- prep: W1 row / B1, biases, W5 column / B5 (f32, verified) --------
__global__ void prep_small(PtrPack P, unsigned char* __restrict__ ws) {
    int t = blockIdx.x * 256 + threadIdx.x;
    if (t < 6144) {
        int idx = t >> 9, e = t & 511;
        int net = idx / 6, i = idx % 6;
        int j = (i & 1) ? 0 : 1;
        float v;
        if (e < 256) v = P.p[1 + net * 10][i * 512 + j * 256 + e];
        else         v = P.p[2 + net * 10][i * 256 + (e - 256)];
        ((float*)(ws + W1B1_OFF))[t] = v;
    } else if (t < 6144 + 9216) {
        int u = t - 6144;
        int idx = u >> 8, e = u & 255;
        int net = idx / 18, rem = idx % 18, i = rem / 3, g = rem % 3;
        ((float*)(ws + BIAS_OFF))[u] = P.p[4 + g * 2 + net * 10][i * 256 + e];
    } else if (t < 6144 + 9216 + 12 * 272) {
        int u = t - 6144 - 9216;
        int idx = u / 272, e = u % 272;
        int net = idx / 6, i = idx % 6;
        int ud = (i & 1) ? 1 : 0;
        float v = 0.f;
        if (e < 256)      v = P.p[9 + net * 10][i * 512 + e * 2 + ud];
        else if (e == 256) v = P.p[10 + net * 10][i * 2 + ud];
        ((float*)(ws + W5_OFF))[idx * 272 + e] = v;
    }
}

// ---------------- main fused kernel ----------------
// r22: r21's frag-order A-tile (conflict-free k-loop, MFMA layer-1) with the
// row tile halved 128 -> 64 to buy a third wave per SIMD:
//   acc 8->4 x f32x16 (64 AGPR), A-tile 64KB->32KB, LDS/block ~34.8KB,
//   __launch_bounds__(256,3) -> 3 blocks/CU (12 waves/CU, was 8).
// Rationale: per-GEMM-pair wall 16.8k cyc vs additive pipe demands ~5k
// (MFMA 2k, LDS 5.1k, L2-W 4.7k, VALU 1k) -> 2 waves/SIMD can't overlap
// the pipes; occupancy is the binding constraint. r19's spill failure was
// the (512,4) cap forcing arch<=64; here budget is 170/wave: 64 acc + ~85
// arch fits. Cost: W traffic per MFMA doubles (L2-resident, shared by 32
// CUs/XCD in lockstep). Gate: WRITE_SIZE stays ~1.5MB (no spills).
#define L_A   0       // 16 kk * 2 rt * 1024 = 32768
#define L_Z0  32768
#define L_Z1  33024
#define L_LD  33280
#define L_RED 33536   // [4 waves][64 rows] f32
#define L_OS  34560   // oS[64]
#define L_TOT 34816

__device__ __forceinline__ unsigned pk2(float a, float b) {
    unsigned short ua = __builtin_bit_cast(unsigned short, (__bf16)a);
    unsigned short ub = __builtin_bit_cast(unsigned short, (__bf16)b);
    return (unsigned)ua | ((unsigned)ub << 16);
}

__global__ __launch_bounds__(256, 3) void realnvp_main(
        const float* __restrict__ x, const unsigned char* __restrict__ ws,
        float* __restrict__ out) {
    __shared__ __align__(16) unsigned char lds[L_TOT];
    const int tid = threadIdx.x;
    const int wv = tid >> 6, lane = tid & 63;
    const int li = lane & 31, hi = lane >> 5;
    float* zA  = (float*)(lds + L_Z0);
    float* zB  = (float*)(lds + L_Z1);
    float* ldt = (float*)(lds + L_LD);
    float* red = (float*)(lds + L_RED);
    float* oSa = (float*)(lds + L_OS);
    const float* w1b1_g = (const float*)(ws + W1B1_OFF);
    const float* bias_g = (const float*)(ws + BIAS_OFF);
    const float* w5_g   = (const float*)(ws + W5_OFF);

    // frag-layout bases (all k-loop/epilogue offsets are compile-time imms)
    const unsigned char* aaBase = lds + L_A + (unsigned)lane * 16;
    unsigned char* const stBase = lds + L_A + (unsigned)(li * 16 + hi * 8);

    if (tid < 64) {
        float2 xv = ((const float2*)x)[blockIdx.x * 64 + tid];
        zA[tid] = logf(xv.x) - logf(1.f - xv.x);
        zB[tid] = logf(xv.y) - logf(1.f - xv.y);
        ldt[tid] = 0.f;
    }
    __syncthreads();

    // shared epilogue: relu -> bf16 pairs -> A-frag stores
    auto storeA = [&](const f32x16* a) {
#pragma unroll
        for (int rt = 0; rt < 2; ++rt)
#pragma unroll
            for (int j2 = 0; j2 < 2; ++j2)
#pragma unroll
                for (int q = 0; q < 4; ++q) {
                    const f32x16& A = a[rt * 2 + j2];
                    unsigned lo = pk2(fmaxf(A[4 * q + 0], 0.f), fmaxf(A[4 * q + 1], 0.f));
                    unsigned h2 = pk2(fmaxf(A[4 * q + 2], 0.f), fmaxf(A[4 * q + 3], 0.f));
                    const unsigned off = (unsigned)((wv * 4 + j2 * 2 + (q >> 1)) * 2048
                                                    + rt * 1024 + (q & 1) * 512);
                    *(uint2*)(stBase + off) = make_uint2(lo, h2);
                }
    };

#pragma unroll 1
    for (int ii = 0; ii < LNUM; ++ii) {
        const int i = 5 - ii;
#pragma unroll 1
        for (int net = 0; net < 2; ++net) {
            // ---- layer 1 as a single-k-step MFMA ----
            {
                const float* w1 = w1b1_g + (net * 6 + i) * 512;
                const float* zArr = (i & 1) ? zA : zB;
                bf16x8 wf[2], af[2];
                const bf16x8 zr = {};
                if (hi == 0) {
#pragma unroll
                    for (int f = 0; f < 2; ++f) {
                        const int n = (wv * 2 + f) * 32 + li;
                        const float W = w1[n], B = w1[256 + n];
                        const __bf16 Wh = (__bf16)W;
                        const __bf16 Wl = (__bf16)(W - (float)Wh);
                        const __bf16 Bh = (__bf16)B;
                        const __bf16 Bl = (__bf16)(B - (float)Bh);
                        bf16x8 t = zr;
                        t[0] = Wh; t[1] = Wl; t[2] = Wh; t[3] = Bh; t[4] = Bl;
                        wf[f] = t;
                    }
#pragma unroll
                    for (int rt = 0; rt < 2; ++rt) {
                        const float z = zArr[rt * 32 + li];
                        const __bf16 zh = (__bf16)z;
                        const __bf16 zl = (__bf16)(z - (float)zh);
                        bf16x8 t = zr;
                        t[0] = zh; t[1] = zh; t[2] = zl;
                        t[3] = (__bf16)1.f; t[4] = (__bf16)1.f;
                        af[rt] = t;
                    }
                } else {
                    wf[0] = zr; wf[1] = zr;
                    af[0] = zr; af[1] = zr;
                }
                f32x16 acc1[4];
#pragma unroll
                for (int u = 0; u < 4; ++u)
#pragma unroll
                    for (int e = 0; e < 16; ++e) acc1[u][e] = 0.f;
#pragma unroll
                for (int rt = 0; rt < 2; ++rt) {
                    acc1[rt * 2 + 0] = __builtin_amdgcn_mfma_f32_32x32x16_bf16(wf[0], af[rt], acc1[rt * 2 + 0], 0, 0, 0);
                    acc1[rt * 2 + 1] = __builtin_amdgcn_mfma_f32_32x32x16_bf16(wf[1], af[rt], acc1[rt * 2 + 1], 0, 0, 0);
                }
                storeA(acc1);
            }
            __syncthreads();
#pragma unroll 1
            for (int g = 0; g < 3; ++g) {
                const int blk = (net * 6 + i) * 3 + g;
                const unsigned char* wbase = ws + (unsigned long)blk * WFRAG_BYTES
                        + (unsigned)(wv >> 1) * 65536 + (unsigned)(wv & 1) * 2048
                        + (unsigned)lane * 16;
                const float* biasl = bias_g + blk * 256 + wv * 64;
                const float* w5 = w5_g + (net * 6 + i) * 272;

                f32x16 acc[4];   // [rt*2 + j]: rows rt*32.., n = wv*64 + j*32 ..
#pragma unroll
                for (int j2 = 0; j2 < 2; ++j2)
#pragma unroll
                    for (int q = 0; q < 4; ++q) {
                        f32x4 bb = *(const f32x4*)(biasl + j2 * 32 + q * 8 + hi * 4);
#pragma unroll
                        for (int rt = 0; rt < 2; ++rt) {
                            acc[rt * 2 + j2][4 * q + 0] = bb[0];
                            acc[rt * 2 + j2][4 * q + 1] = bb[1];
                            acc[rt * 2 + j2][4 * q + 2] = bb[2];
                            acc[rt * 2 + j2][4 * q + 3] = bb[3];
                        }
                    }
                // weight ring (global->reg, 3 k-steps deep) + act ping-pong
                bf16x8 wq[3][2];
#pragma unroll
                for (int p = 0; p < 3; ++p) {
                    wq[p][0] = *(const bf16x8*)(wbase + p * 4096);
                    wq[p][1] = *(const bf16x8*)(wbase + p * 4096 + 1024);
                }
                bf16x8 aa[2][2];
#pragma unroll
                for (int rt = 0; rt < 2; ++rt)
                    aa[0][rt] = *(const bf16x8*)(aaBase + rt * 1024);
#pragma unroll
                for (int k = 0; k < 16; ++k) {
                    const int cur = k & 1, nxt = cur ^ 1;
                    if (k < 15) {
#pragma unroll
                        for (int rt = 0; rt < 2; ++rt)
                            aa[nxt][rt] = *(const bf16x8*)(aaBase + (k + 1) * 2048 + rt * 1024);
                    }
                    __builtin_amdgcn_s_setprio(1);
#pragma unroll
                    for (int rt = 0; rt < 2; ++rt) {
                        acc[rt * 2 + 0] = __builtin_amdgcn_mfma_f32_32x32x16_bf16(wq[k % 3][0], aa[cur][rt], acc[rt * 2 + 0], 0, 0, 0);
                        acc[rt * 2 + 1] = __builtin_amdgcn_mfma_f32_32x32x16_bf16(wq[k % 3][1], aa[cur][rt], acc[rt * 2 + 1], 0, 0, 0);
                    }
                    __builtin_amdgcn_s_setprio(0);
                    if (k < 13) {
                        wq[k % 3][0] = *(const bf16x8*)(wbase + (k + 3) * 4096);
                        wq[k % 3][1] = *(const bf16x8*)(wbase + (k + 3) * 4096 + 1024);
                    }
                }
                __syncthreads();   // all waves done reading A
                if (g < 2) {
                    storeA(acc);
                    __syncthreads();
                } else {
                    // layer-5 dot over this wave's n-slice, then cross-wave reduce
                    float part[2] = {0.f, 0.f};
#pragma unroll
                    for (int j2 = 0; j2 < 2; ++j2)
#pragma unroll
                        for (int q = 0; q < 4; ++q) {
                            f32x4 ww = *(const f32x4*)(w5 + wv * 64 + j2 * 32 + q * 8 + hi * 4);
#pragma unroll
                            for (int rt = 0; rt < 2; ++rt)
#pragma unroll
                                for (int c = 0; c < 4; ++c)
                                    part[rt] += fmaxf(acc[rt * 2 + j2][4 * q + c], 0.f) * ww[c];
                        }
#pragma unroll
                    for (int rt = 0; rt < 2; ++rt) part[rt] += __shfl_xor(part[rt], 32);
                    if (hi == 0) {
#pragma unroll
                        for (int rt = 0; rt < 2; ++rt) red[wv * 64 + rt * 32 + li] = part[rt];
                    }
                    __syncthreads();
                    if (tid < 64) {
                        const float o = red[tid] + red[64 + tid] + red[128 + tid] + red[192 + tid]
                                        + w5[256];
                        if (net == 0) {
                            oSa[tid] = o;
                        } else {
                            const float s = tanhf(oSa[tid]);
                            const float e = expf(-s);
                            if (i & 1) zB[tid] = (zB[tid] - o) * e;
                            else       zA[tid] = (zA[tid] - o) * e;
                            ldt[tid] -= s;
                        }
                    }
                    __syncthreads();
                }
            }
        }
    }
    if (tid < 64) {
        const int row = blockIdx.x * 64 + tid;
        ((float2*)out)[row] = make_float2(1.f / (1.f + expf(-zA[tid])),
                                          1.f / (1.f + expf(-zB[tid])));
        out[2 * BATCH + row] = ldt[tid];
    }
}

extern "C" void kernel_launch(void* const* d_in, const int* in_sizes, int n_in,
                              void* d_out, int out_size, void* d_ws, size_t ws_size,
                              hipStream_t stream) {
    if (ws_size < WS_NEEDED) return;
    PtrPack P;
    for (int k = 0; k < 21; ++k) P.p[k] = (const float*)d_in[k];
    unsigned char* ws = (unsigned char*)d_ws;
    prep_w<<<dim3(1152), dim3(256), 0, stream>>>(P, ws);
    prep_small<<<dim3(73), dim3(256), 0, stream>>>(P, ws);
    realnvp_main<<<dim3(2048), dim3(256), 0, stream>>>((const float*)d_in[0], ws, (float*)d_out);
}

// Round 5
// 532.104 us; speedup vs baseline: 1.1243x; 1.1243x over previous
//
#include <hip/hip_runtime.h>
#include <hip/hip_bf16.h>

#define LNUM 6
#define BATCH 131072

typedef __bf16 bf16x8 __attribute__((ext_vector_type(8)));
typedef float f32x16 __attribute__((ext_vector_type(16)));
typedef float f32x4  __attribute__((ext_vector_type(4)));

// ---------------- ws layout ----------------
// 36 W blocks, each 256x256 bf16 = 131072 B:
// [nh(2)][kk(16)][nti(4)][lane(64)][16B]
//   n = (nh*4+nti)*32 + (l&31), k = kk*16 + (l>>5)*8 + jj
#define WFRAG_BYTES 131072ul
#define W1B1_OFF 4718592ul   // 12 x (256 f32 W1row || 256 f32 B1)
#define BIAS_OFF 4743168ul   // 36 x 256 f32 (B2/B3/B4)
#define W5_OFF   4780032ul   // 12 x 272 f32 (W5 column || B5 || pad)
#define WS_NEEDED 4793088ul

struct PtrPack { const float* p[21]; };

// -------- prep: pack W2/W3/W4 into MFMA fragment order (verified r4-r17) --------
__global__ void prep_w(PtrPack P, unsigned char* __restrict__ ws) {
    int t = blockIdx.x * 256 + threadIdx.x;
    int blk = t >> 13;
    int e8  = t & 8191;
    int nh  = e8 >> 12;
    int kk  = (e8 >> 8) & 15;
    int nti = (e8 >> 6) & 3;
    int l   = e8 & 63;
    int nt = nh * 4 + nti;
    int n  = nt * 32 + (l & 31);
    int k0 = kk * 16 + (l >> 5) * 8;
    int net = blk / 18, rem = blk % 18;
    int i = rem / 3, g = rem % 3;
    const float* src = P.p[3 + g * 2 + net * 10] + i * 65536;
    bf16x8 v;
#pragma unroll
    for (int jj = 0; jj < 8; ++jj) v[jj] = (__bf16)src[(k0 + jj) * 256 + n];
    *(bf16x8*)(ws + (unsigned long)blk * WFRAG_BYTES + (unsigned)e8 * 16) = v;
}

// -------- prep: W1 row / B1, biases, W5 column / B5 (f32, verified) --------
__global__ void prep_small(PtrPack P, unsigned char* __restrict__ ws) {
    int t = blockIdx.x * 256 + threadIdx.x;
    if (t < 6144) {
        int idx = t >> 9, e = t & 511;
        int net = idx / 6, i = idx % 6;
        int j = (i & 1) ? 0 : 1;
        float v;
        if (e < 256) v = P.p[1 + net * 10][i * 512 + j * 256 + e];
        else         v = P.p[2 + net * 10][i * 256 + (e - 256)];
        ((float*)(ws + W1B1_OFF))[t] = v;
    } else if (t < 6144 + 9216) {
        int u = t - 6144;
        int idx = u >> 8, e = u & 255;
        int net = idx / 18, rem = idx % 18, i = rem / 3, g = rem % 3;
        ((float*)(ws + BIAS_OFF))[u] = P.p[4 + g * 2 + net * 10][i * 256 + e];
    } else if (t < 6144 + 9216 + 12 * 272) {
        int u = t - 6144 - 9216;
        int idx = u / 272, e = u % 272;
        int net = idx / 6, i = idx % 6;
        int ud = (i & 1) ? 1 : 0;
        float v = 0.f;
        if (e < 256)      v = P.p[9 + net * 10][i * 512 + e * 2 + ud];
        else if (e == 256) v = P.p[10 + net * 10][i * 2 + ud];
        ((float*)(ws + W5_OFF))[idx * 272 + e] = v;
    }
}

// ---------------- main fused kernel ----------------
// r23 = r21 (proven 523us: 128 rows, 4 waves x 64-col slices, frag-order A,
// 2 blocks/CU) + cross-GEMM pipelining:
//  - RAW barriers (lgkmcnt(0)+s_barrier, NO vmcnt drain) in the GEMM chain:
//    __syncthreads' forced vmcnt(0) was killing any prefetch across phases.
//    Legal: only LDS (A-tile) needs cross-wave ordering; ws is read-only.
//  - cross-GEMM wq prefetch: after g's k-loop, issue g+1's k=0..2 weights
//    into the freed ring slots (phase rotates 16%3=1 per GEMM -> template
//    PH makes slot indices static). L2 latency hides under storeA+barriers.
//    Pass-start g0 wq issues before layer1, hides under layer1.
//  - fast transcendentals (__logf/__expf, overflow-safe tanh) in
//    prologue/tail/finale (error ~1e-6 << 4e-3 budget).
// Gates: WRITE_SIZE ~1536 KB (no spills), VGPR <= 128.
#define L_A   0       // 16*4096 = 65536
#define L_Z0  65536
#define L_Z1  66048
#define L_LD  66560
#define L_RED 67072   // [4 waves][128 rows] f32
#define L_OS  69120   // oS[128]
#define L_TOT 69632

__device__ __forceinline__ unsigned pk2(float a, float b) {
    unsigned short ua = __builtin_bit_cast(unsigned short, (__bf16)a);
    unsigned short ub = __builtin_bit_cast(unsigned short, (__bf16)b);
    return (unsigned)ua | ((unsigned)ub << 16);
}

// lgkm-only barrier: orders LDS, leaves global loads (vmcnt) in flight.
__device__ __forceinline__ void rawbar() {
    __builtin_amdgcn_sched_barrier(0);
    asm volatile("s_waitcnt lgkmcnt(0)" ::: "memory");
    __builtin_amdgcn_s_barrier();
    __builtin_amdgcn_sched_barrier(0);
}

// relu -> bf16 pairs -> A-frag stores (conflict-free pattern, verified r21)
__device__ __forceinline__ void storeA_frag(unsigned char* stBase, int wv,
                                            const f32x16* a) {
#pragma unroll
    for (int rt = 0; rt < 4; ++rt)
#pragma unroll
        for (int j2 = 0; j2 < 2; ++j2)
#pragma unroll
            for (int q = 0; q < 4; ++q) {
                const f32x16& A = a[rt * 2 + j2];
                unsigned lo = pk2(fmaxf(A[4 * q + 0], 0.f), fmaxf(A[4 * q + 1], 0.f));
                unsigned h2 = pk2(fmaxf(A[4 * q + 2], 0.f), fmaxf(A[4 * q + 3], 0.f));
                const unsigned off = (unsigned)((wv * 4 + j2 * 2 + (q >> 1)) * 4096
                                                + rt * 1024 + (q & 1) * 512);
                *(uint2*)(stBase + off) = make_uint2(lo, h2);
            }
}

template<int PH, bool TAIL>
__device__ __forceinline__ void gemm_run(
        const unsigned char* __restrict__ wbase,
        const unsigned char* __restrict__ wnext,
        bf16x8 (&wq)[3][2],
        const float* __restrict__ biasl, const float* __restrict__ w5,
        const unsigned char* __restrict__ aaBase, unsigned char* __restrict__ stBase,
        float* __restrict__ red, float* __restrict__ zA, float* __restrict__ zB,
        float* __restrict__ ldt, float* __restrict__ oSa,
        int i, int net, int wv, int li, int hi, int tid)
{
    f32x16 acc[8];   // [rt*2 + j2]: rows rt*32.., n = wv*64 + j2*32 ..
#pragma unroll
    for (int j2 = 0; j2 < 2; ++j2)
#pragma unroll
        for (int q = 0; q < 4; ++q) {
            f32x4 bb = *(const f32x4*)(biasl + j2 * 32 + q * 8 + hi * 4);
#pragma unroll
            for (int rt = 0; rt < 4; ++rt) {
                acc[rt * 2 + j2][4 * q + 0] = bb[0];
                acc[rt * 2 + j2][4 * q + 1] = bb[1];
                acc[rt * 2 + j2][4 * q + 2] = bb[2];
                acc[rt * 2 + j2][4 * q + 3] = bb[3];
            }
        }
    bf16x8 aa[2][4];
#pragma unroll
    for (int rt = 0; rt < 4; ++rt)
        aa[0][rt] = *(const bf16x8*)(aaBase + rt * 1024);
#pragma unroll
    for (int k = 0; k < 16; ++k) {
        const int cur = k & 1, nxt = cur ^ 1;
        if (k < 15) {
#pragma unroll
            for (int rt = 0; rt < 4; ++rt)
                aa[nxt][rt] = *(const bf16x8*)(aaBase + (k + 1) * 4096 + rt * 1024);
        }
        __builtin_amdgcn_s_setprio(1);
#pragma unroll
        for (int rt = 0; rt < 4; ++rt) {
            acc[rt * 2 + 0] = __builtin_amdgcn_mfma_f32_32x32x16_bf16(wq[(k + PH) % 3][0], aa[cur][rt], acc[rt * 2 + 0], 0, 0, 0);
            acc[rt * 2 + 1] = __builtin_amdgcn_mfma_f32_32x32x16_bf16(wq[(k + PH) % 3][1], aa[cur][rt], acc[rt * 2 + 1], 0, 0, 0);
        }
        __builtin_amdgcn_s_setprio(0);
        if (k < 13) {
            wq[(k + PH) % 3][0] = *(const bf16x8*)(wbase + (k + 3) * 4096);
            wq[(k + PH) % 3][1] = *(const bf16x8*)(wbase + (k + 3) * 4096 + 1024);
        }
    }
    if constexpr (!TAIL) {
        // prefetch next GEMM's first 3 k-steps into the freed ring slots;
        // stays in flight across the raw barriers (no vmcnt drain).
#pragma unroll
        for (int j = 0; j < 3; ++j) {
            wq[(j + PH + 1) % 3][0] = *(const bf16x8*)(wnext + j * 4096);
            wq[(j + PH + 1) % 3][1] = *(const bf16x8*)(wnext + j * 4096 + 1024);
        }
    }
    rawbar();   // all waves done reading A
    if constexpr (!TAIL) {
        storeA_frag(stBase, wv, acc);
        rawbar();
    } else {
        // layer-5 dot over this wave's n-slice, then cross-wave reduce
        float part[4] = {0.f, 0.f, 0.f, 0.f};
#pragma unroll
        for (int j2 = 0; j2 < 2; ++j2)
#pragma unroll
            for (int q = 0; q < 4; ++q) {
                f32x4 ww = *(const f32x4*)(w5 + wv * 64 + j2 * 32 + q * 8 + hi * 4);
#pragma unroll
                for (int rt = 0; rt < 4; ++rt)
#pragma unroll
                    for (int c = 0; c < 4; ++c)
                        part[rt] += fmaxf(acc[rt * 2 + j2][4 * q + c], 0.f) * ww[c];
            }
#pragma unroll
        for (int rt = 0; rt < 4; ++rt) part[rt] += __shfl_xor(part[rt], 32);
        if (hi == 0) {
#pragma unroll
            for (int rt = 0; rt < 4; ++rt) red[wv * 128 + rt * 32 + li] = part[rt];
        }
        __syncthreads();
        if (tid < 128) {
            const float o = red[tid] + red[128 + tid] + red[256 + tid] + red[384 + tid]
                            + w5[256];
            if (net == 0) {
                oSa[tid] = o;
            } else {
                const float so = oSa[tid];
                const float t2 = __expf(-2.f * fabsf(so));
                const float s  = copysignf((1.f - t2) / (1.f + t2), so);
                const float e  = __expf(-s);
                if (i & 1) zB[tid] = (zB[tid] - o) * e;
                else       zA[tid] = (zA[tid] - o) * e;
                ldt[tid] -= s;
            }
        }
        __syncthreads();
    }
}

__global__ __launch_bounds__(256, 2) void realnvp_main(
        const float* __restrict__ x, const unsigned char* __restrict__ ws,
        float* __restrict__ out) {
    __shared__ __align__(16) unsigned char lds[L_TOT];
    const int tid = threadIdx.x;
    const int wv = tid >> 6, lane = tid & 63;
    const int li = lane & 31, hi = lane >> 5;
    float* zA  = (float*)(lds + L_Z0);
    float* zB  = (float*)(lds + L_Z1);
    float* ldt = (float*)(lds + L_LD);
    float* red = (float*)(lds + L_RED);
    float* oSa = (float*)(lds + L_OS);
    const float* w1b1_g = (const float*)(ws + W1B1_OFF);
    const float* bias_g = (const float*)(ws + BIAS_OFF);
    const float* w5_g   = (const float*)(ws + W5_OFF);

    // frag-layout bases (all k-loop/epilogue offsets are compile-time imms)
    const unsigned char* aaBase = lds + L_A + (unsigned)lane * 16;
    unsigned char* const stBase = lds + L_A + (unsigned)(li * 16 + hi * 8);
    const unsigned woff = (unsigned)((wv >> 1) * 65536 + (wv & 1) * 2048 + lane * 16);

    if (tid < 128) {
        float2 xv = ((const float2*)x)[blockIdx.x * 128 + tid];
        zA[tid] = __logf(xv.x) - __logf(1.f - xv.x);
        zB[tid] = __logf(xv.y) - __logf(1.f - xv.y);
        ldt[tid] = 0.f;
    }
    __syncthreads();

    bf16x8 wq[3][2];

#pragma unroll 1
    for (int ii = 0; ii < LNUM; ++ii) {
        const int i = 5 - ii;
#pragma unroll 1
        for (int net = 0; net < 2; ++net) {
            const int pbase = (net * 6 + i) * 3;
            const unsigned char* wb0 = ws + (unsigned long)pbase * WFRAG_BYTES + woff;
            const unsigned char* wb1 = wb0 + WFRAG_BYTES;
            const unsigned char* wb2 = wb1 + WFRAG_BYTES;
            const float* biasp = bias_g + pbase * 256 + wv * 64;
            const float* w5 = w5_g + (net * 6 + i) * 272;

            // pass-start: preload g0's first 3 k-steps (PH=0 -> slots 0,1,2);
            // latency hides under layer1 (raw barrier keeps them in flight).
#pragma unroll
            for (int p = 0; p < 3; ++p) {
                wq[p][0] = *(const bf16x8*)(wb0 + p * 4096);
                wq[p][1] = *(const bf16x8*)(wb0 + p * 4096 + 1024);
            }

            // ---- layer 1 as a single-k-step MFMA (verified r21) ----
            {
                const float* w1 = w1b1_g + (net * 6 + i) * 512;
                const float* zArr = (i & 1) ? zA : zB;
                bf16x8 wf[2], af[4];
                const bf16x8 zr = {};
                if (hi == 0) {
#pragma unroll
                    for (int f = 0; f < 2; ++f) {
                        const int n = (wv * 2 + f) * 32 + li;
                        const float W = w1[n], B = w1[256 + n];
                        const __bf16 Wh = (__bf16)W;
                        const __bf16 Wl = (__bf16)(W - (float)Wh);
                        const __bf16 Bh = (__bf16)B;
                        const __bf16 Bl = (__bf16)(B - (float)Bh);
                        bf16x8 t = zr;
                        t[0] = Wh; t[1] = Wl; t[2] = Wh; t[3] = Bh; t[4] = Bl;
                        wf[f] = t;
                    }
#pragma unroll
                    for (int rt = 0; rt < 4; ++rt) {
                        const float z = zArr[rt * 32 + li];
                        const __bf16 zh = (__bf16)z;
                        const __bf16 zl = (__bf16)(z - (float)zh);
                        bf16x8 t = zr;
                        t[0] = zh; t[1] = zh; t[2] = zl;
                        t[3] = (__bf16)1.f; t[4] = (__bf16)1.f;
                        af[rt] = t;
                    }
                } else {
                    wf[0] = zr; wf[1] = zr;
                    af[0] = zr; af[1] = zr; af[2] = zr; af[3] = zr;
                }
                f32x16 acc1[8];
#pragma unroll
                for (int u = 0; u < 8; ++u)
#pragma unroll
                    for (int e = 0; e < 16; ++e) acc1[u][e] = 0.f;
#pragma unroll
                for (int rt = 0; rt < 4; ++rt) {
                    acc1[rt * 2 + 0] = __builtin_amdgcn_mfma_f32_32x32x16_bf16(wf[0], af[rt], acc1[rt * 2 + 0], 0, 0, 0);
                    acc1[rt * 2 + 1] = __builtin_amdgcn_mfma_f32_32x32x16_bf16(wf[1], af[rt], acc1[rt * 2 + 1], 0, 0, 0);
                }
                storeA_frag(stBase, wv, acc1);
            }
            rawbar();

            gemm_run<0, false>(wb0, wb1, wq, biasp,       w5, aaBase, stBase,
                               red, zA, zB, ldt, oSa, i, net, wv, li, hi, tid);
            gemm_run<1, false>(wb1, wb2, wq, biasp + 256, w5, aaBase, stBase,
                               red, zA, zB, ldt, oSa, i, net, wv, li, hi, tid);
            gemm_run<2, true >(wb2, wb2, wq, biasp + 512, w5, aaBase, stBase,
                               red, zA, zB, ldt, oSa, i, net, wv, li, hi, tid);
        }
    }
    if (tid < 128) {
        const int row = blockIdx.x * 128 + tid;
        ((float2*)out)[row] = make_float2(1.f / (1.f + __expf(-zA[tid])),
                                          1.f / (1.f + __expf(-zB[tid])));
        out[2 * BATCH + row] = ldt[tid];
    }
}

extern "C" void kernel_launch(void* const* d_in, const int* in_sizes, int n_in,
                              void* d_out, int out_size, void* d_ws, size_t ws_size,
                              hipStream_t stream) {
    if (ws_size < WS_NEEDED) return;
    PtrPack P;
    for (int k = 0; k < 21; ++k) P.p[k] = (const float*)d_in[k];
    unsigned char* ws = (unsigned char*)d_ws;
    prep_w<<<dim3(1152), dim3(256), 0, stream>>>(P, ws);
    prep_small<<<dim3(73), dim3(256), 0, stream>>>(P, ws);
    realnvp_main<<<dim3(1024), dim3(256), 0, stream>>>((const float*)d_in[0], ws, (float*)d_out);
}